// Round 4
// baseline (934.095 us; speedup 1.0000x reference)
//
#include <hip/hip_runtime.h>
#include <math.h>

#define N_NODES 50000
#define N_EDGES 160000
#define NB 32
#define C1N 25000
#define C2N 12500

// ---- workspace layout (in floats) ----
#define OFF_AGG1 0
#define SZ_AGG1 (N_NODES*32)
#define OFF_X2   (OFF_AGG1+SZ_AGG1)
#define SZ_X2    (C1N*32)
#define OFF_AGG2 (OFF_X2+SZ_X2)
#define SZ_AGG2  (C1N*64)
#define OFF_X4   (OFF_AGG2+SZ_AGG2)
#define SZ_X4    (C2N*64)
#define NEG_TOTAL (OFF_X4+SZ_X4)            // filled with -inf
#define OFF_P2S  NEG_TOTAL                  // pos2 sums  C1*2
#define OFF_CNT1 (OFF_P2S + C1N*2)          // counts     C1
#define OFF_GSUM (OFF_CNT1 + C1N)           // B*64
#define OFF_GCNT (OFF_GSUM + NB*64)         // B
#define OFF_CMAX (OFF_GCNT + NB)            // 1 (+3 pad)
#define OFF_B2I  (OFF_CMAX + 4)             // batch2 int C1
#define OFF_B3I  (OFF_B2I + C1N)            // batch3 int C2
#define ZERO_END (OFF_B3I + C2N)            // zero-filled up to here
#define OFF_POS2 (ZERO_END)                 // C1*2
#define OFF_ES   (OFF_POS2 + C1N*2)         // e2src int E
#define OFF_ED   (OFF_ES + N_EDGES)         // e2dst int E
#define OFF_CART (OFF_ED + N_EDGES)         // E*2
#define OFF_BB1  (OFF_CART + N_EDGES*2)     // 832*32 bf16 = 13312 floats
#define OFF_BB2  (OFF_BB1 + 13312)          // 1664*32 bf16 = 26624 floats
#define OFF_Y    (OFF_BB2 + 26624)          // y buffer: 41.6M bf16 = 20.8M floats (reused)

typedef __attribute__((ext_vector_type(8))) short short8;
typedef __attribute__((ext_vector_type(8))) unsigned short ushort8;
typedef __attribute__((ext_vector_type(4))) float f32x4;

__device__ __forceinline__ void atomicMaxFloat(float* addr, float v) {
    if (v >= 0.0f) atomicMax((int*)addr, __float_as_int(v + 0.0f)); // +0.0 canonicalizes -0
    else           atomicMin((unsigned int*)addr, __float_as_uint(v));
}
__device__ __forceinline__ float eluf(float v) { return v > 0.0f ? v : expm1f(v); }
__device__ __forceinline__ unsigned short f2bf(float f) {
    unsigned int u = __float_as_uint(f);
    u += 0x7FFFu + ((u >> 16) & 1u);   // round-to-nearest-even
    return (unsigned short)(u >> 16);
}
__device__ __forceinline__ float bf2f(unsigned short h) {
    return __uint_as_float(((unsigned int)h) << 16);
}

__global__ void k_init(float* ws) {
    int i = blockIdx.x*256 + threadIdx.x;
    if (i < ZERO_END) ws[i] = (i < NEG_TOTAL) ? -__builtin_inff() : 0.0f;
}

__global__ void k_pool1_aux(const float* __restrict__ pos, const int* __restrict__ batch,
                            const int* __restrict__ cl1, float* ws) {
    int n = blockIdx.x*256 + threadIdx.x;
    if (n >= N_NODES) return;
    int c = cl1[n];
    atomicAdd(&ws[OFF_P2S + c*2],     pos[n*2]);
    atomicAdd(&ws[OFF_P2S + c*2 + 1], pos[n*2+1]);
    atomicAdd(&ws[OFF_CNT1 + c], 1.0f);
    atomicMax((int*)(ws+OFF_B2I) + c, batch[n]);
}

// ---- weight swizzle: B[i][c] (c = h*O+o for h<25, bias rows at c>=25*O) -> bf16
// fragment layout: out[t*512 + l*8 + j] = B[(l>>4)*8+j][t*16+(l&15)]
template<int O>
__global__ void k_swz(const float* __restrict__ w2, const float* __restrict__ b2,
                      unsigned short* __restrict__ Bb) {
    const int CC = 26*O;
    int idx = blockIdx.x*256 + threadIdx.x;
    if (idx >= CC*32) return;
    int t = idx >> 9, l = (idx >> 3) & 63, j = idx & 7;
    int i = (l >> 4)*8 + j;
    int c = t*16 + (l & 15);
    float v;
    if (c < 25*O) v = w2[(c/O)*(32*O) + i*O + (c % O)];
    else          v = b2[i*O + (c - 25*O)];
    Bb[idx] = f2bf(v);
}

// ---- phase A: y[n, c] = sum_i bf16(x[n,i]) * Bb[i,c]   (MFMA 16x16x32, K=32 in one step)
template<int NN, int CC>
__global__ __launch_bounds__(256) void k_phaseA(const float* __restrict__ X,
                                                const unsigned short* __restrict__ Bb,
                                                unsigned short* __restrict__ Y) {
    __shared__ __align__(16) unsigned short Bs[CC*32];
    int tid = threadIdx.x;
    for (int idx = tid; idx < CC*4; idx += 256)
        ((uint4*)Bs)[idx] = ((const uint4*)Bb)[idx];
    __syncthreads();
    int l = tid & 63, w = tid >> 6;
    int nbase = blockIdx.x*64 + w*16;
    int n = nbase + (l & 15);
    int nc = n < NN ? n : NN-1;
    int k0 = (l >> 4) * 8;
    const float* xr = X + nc*32 + k0;
    short8 av;
    #pragma unroll
    for (int j = 0; j < 8; ++j) av[j] = (short)f2bf(xr[j]);
    int rbase = nbase + (l >> 4)*4;
    int cl = l & 15;
    for (int t = 0; t < CC/16; ++t) {
        short8 bv = *(const short8*)&Bs[t*512 + l*8];
        f32x4 d = {0.f, 0.f, 0.f, 0.f};
        d = __builtin_amdgcn_mfma_f32_16x16x32_bf16(av, bv, d, 0, 0, 0);
        int c = t*16 + cl;
        #pragma unroll
        for (int r = 0; r < 4; ++r) {
            int row = rbase + r;
            if (row < NN) Y[(size_t)row*CC + c] = f2bf(d[r]);
        }
    }
}

// ---- edge phase: msg[e,o] = sum_{h=0..25} r[e,h] * y[src_e, h*O+o];  r[25]=1
template<int O, int EPB>
__global__ __launch_bounds__(256) void k_edge(
    const unsigned short* __restrict__ Y,
    const float* __restrict__ w1, const float* __restrict__ b1,
    const int* __restrict__ srcArr, const int* __restrict__ dstArr,
    const float* __restrict__ eaArr, const float* __restrict__ cmaxp,
    float* __restrict__ agg, int selfskip)
{
    const int HO = 26*O;
    const int TPE = O/8;
    __shared__ float r_s[EPB][27];
    __shared__ int src_s[EPB], dst_s[EPB];
    int tid = threadIdx.x;
    int e0 = blockIdx.x * EPB;
    if (tid < EPB) { src_s[tid] = srcArr[e0+tid]; dst_s[tid] = dstArr[e0+tid]; }
    float sc = 1.0f, off = 0.0f;
    if (cmaxp) { sc = 0.5f / *cmaxp; off = 0.5f; }
    for (int idx = tid; idx < EPB*25; idx += 256) {
        int e = idx / 25, h = idx - e*25;
        float a0 = eaArr[(e0+e)*2]     * sc + off;
        float a1 = eaArr[(e0+e)*2 + 1] * sc + off;
        r_s[e][h] = fmaxf(a0*w1[h] + a1*w1[25+h] + b1[h], 0.0f);
    }
    if (tid < EPB) r_s[tid][25] = 1.0f;
    __syncthreads();
    int el = tid / TPE, o0 = (tid % TPE) * 8;
    int s = src_s[el], d = dst_s[el];
    float acc[8] = {0,0,0,0,0,0,0,0};
    const unsigned short* yr = Y + (size_t)s*HO + o0;
    for (int h = 0; h < 26; ++h) {
        float rv = r_s[el][h];
        ushort8 yv = *(const ushort8*)(yr + h*O);
        #pragma unroll
        for (int j = 0; j < 8; ++j)
            acc[j] += rv * bf2f(yv[j]);
    }
    if (!selfskip || s != d) {
        #pragma unroll
        for (int j = 0; j < 8; ++j)
            atomicMaxFloat(&agg[d*O + o0 + j], acc[j]);
    }
}

__global__ void k_conv1_final(const float* __restrict__ x, const float* __restrict__ root1,
                              const float* __restrict__ bias1, const int* __restrict__ cl1,
                              float* ws) {
    __shared__ float xs[256];
    int tid = threadIdx.x;
    int n0 = blockIdx.x*8;                       // 50000 = 8*6250 exact
    xs[tid] = x[(n0 + (tid>>5))*32 + (tid&31)];
    __syncthreads();
    int n = n0 + (tid>>5), o = tid & 31;
    float v = ws[OFF_AGG1 + n*32 + o];
    if (v == -__builtin_inff()) v = 0.0f;
    float acc = bias1[o];
    const float* xr = xs + (tid>>5)*32;
    #pragma unroll
    for (int i = 0; i < 32; ++i) acc += xr[i]*root1[i*32+o];
    v = eluf(v + acc);
    atomicMaxFloat(&ws[OFF_X2 + cl1[n]*32 + o], v);
}

__global__ void k_pos2div(float* ws) {
    int i = blockIdx.x*256 + threadIdx.x;
    if (i >= C1N*2) return;
    int c = i >> 1;
    ws[OFF_POS2 + i] = ws[OFF_P2S + i] / fmaxf(ws[OFF_CNT1 + c], 1.0f);
}

__global__ void k_cart1(const int* __restrict__ eidx, const int* __restrict__ cl1,
                        float* ws) {
    int e = blockIdx.x*256 + threadIdx.x;
    float m = 0.0f;
    if (e < N_EDGES) {
        int s = cl1[eidx[e]], d = cl1[eidx[N_EDGES+e]];
        ((int*)(ws+OFF_ES))[e] = s;
        ((int*)(ws+OFF_ED))[e] = d;
        float cx = ws[OFF_POS2 + d*2]     - ws[OFF_POS2 + s*2];
        float cy = ws[OFF_POS2 + d*2 + 1] - ws[OFF_POS2 + s*2 + 1];
        ws[OFF_CART + e*2] = cx; ws[OFF_CART + e*2 + 1] = cy;
        m = fmaxf(fabsf(cx), fabsf(cy));
    }
    #pragma unroll
    for (int off = 32; off; off >>= 1) m = fmaxf(m, __shfl_xor(m, off));
    if ((threadIdx.x & 63) == 0) atomicMax((int*)(ws+OFF_CMAX), __float_as_int(m));
}

__global__ void k_conv2_final(const float* __restrict__ root2, const float* __restrict__ bias2,
                              const int* __restrict__ cl2, float* ws) {
    __shared__ float xs[128];
    int tid = threadIdx.x;
    int c0 = blockIdx.x*4;                       // 25000 = 4*6250 exact
    if (tid < 128) xs[tid] = ws[OFF_X2 + (c0 + (tid>>5))*32 + (tid&31)];
    __syncthreads();
    int c = c0 + (tid>>6), o = tid & 63;
    float v = ws[OFF_AGG2 + c*64 + o];
    if (v == -__builtin_inff()) v = 0.0f;
    float acc = bias2[o];
    const float* xr = xs + (tid>>6)*32;
    #pragma unroll
    for (int i = 0; i < 32; ++i) acc += xr[i]*root2[i*64+o];
    v = eluf(v + acc);
    int c2 = cl2[c];
    atomicMaxFloat(&ws[OFF_X4 + c2*64 + o], v);
    if (o == 0) atomicMax((int*)(ws+OFF_B3I) + c2, ((int*)(ws+OFF_B2I))[c]);
}

__global__ void k_gpool(float* ws) {
    int idx = blockIdx.x*256 + threadIdx.x;
    if (idx >= C2N*64) return;
    int c = idx >> 6, o = idx & 63;
    float v = ws[OFF_X4 + idx];
    if (v == -__builtin_inff()) v = 0.0f;
    int b = ((int*)(ws+OFF_B3I))[c];
    atomicAdd(&ws[OFF_GSUM + b*64 + o], v);
    if (o == 0) atomicAdd(&ws[OFF_GCNT + b], 1.0f);
}

__global__ __launch_bounds__(256) void k_head(
    const float* __restrict__ fc1w, const float* __restrict__ fc1b,
    const float* __restrict__ fc2w, const float* __restrict__ fc2b,
    const float* __restrict__ ws, float* __restrict__ out) {
    __shared__ float g_s[32*64], h_s[32*128], l_s[32*32];
    int tid = threadIdx.x;
    for (int idx = tid; idx < 32*64; idx += 256) {
        int b = idx >> 6;
        g_s[idx] = ws[OFF_GSUM + idx] / fmaxf(ws[OFF_GCNT + b], 1.0f);
    }
    __syncthreads();
    for (int idx = tid; idx < 32*128; idx += 256) {
        int b = idx >> 7, f = idx & 127;
        float a = fc1b[f];
        #pragma unroll 8
        for (int i = 0; i < 64; ++i) a += g_s[b*64+i]*fc1w[i*128+f];
        h_s[idx] = eluf(a);
    }
    __syncthreads();
    for (int idx = tid; idx < 32*32; idx += 256) {
        int b = idx >> 5, o = idx & 31;
        float a = fc2b[o];
        #pragma unroll 8
        for (int i = 0; i < 128; ++i) a += h_s[b*128+i]*fc2w[i*32+o];
        l_s[idx] = a;
    }
    __syncthreads();
    if (tid < 32) {
        int b = tid;
        float m = -__builtin_inff();
        for (int o = 0; o < 32; ++o) m = fmaxf(m, l_s[b*32+o]);
        float s = 0.0f;
        for (int o = 0; o < 32; ++o) s += expf(l_s[b*32+o]-m);
        float lg = logf(s);
        for (int o = 0; o < 32; ++o) out[b*32+o] = l_s[b*32+o]-m-lg;
    }
}

extern "C" void kernel_launch(void* const* d_in, const int* in_sizes, int n_in,
                              void* d_out, int out_size, void* d_ws, size_t ws_size,
                              hipStream_t stream) {
    const float* x    = (const float*)d_in[0];
    const float* pos  = (const float*)d_in[1];
    const float* ea   = (const float*)d_in[2];
    const int*   eidx = (const int*)  d_in[3];
    const int*   batch= (const int*)  d_in[4];
    const int*   cl1  = (const int*)  d_in[5];
    const int*   cl2  = (const int*)  d_in[6];
    const float* n1w1 = (const float*)d_in[7];
    const float* n1b1 = (const float*)d_in[8];
    const float* n1w2 = (const float*)d_in[9];
    const float* n1b2 = (const float*)d_in[10];
    const float* root1= (const float*)d_in[11];
    const float* bias1= (const float*)d_in[12];
    const float* n2w1 = (const float*)d_in[13];
    const float* n2b1 = (const float*)d_in[14];
    const float* n2w2 = (const float*)d_in[15];
    const float* n2b2 = (const float*)d_in[16];
    const float* root2= (const float*)d_in[17];
    const float* bias2= (const float*)d_in[18];
    const float* fc1w = (const float*)d_in[19];
    const float* fc1b = (const float*)d_in[20];
    const float* fc2w = (const float*)d_in[21];
    const float* fc2b = (const float*)d_in[22];
    float* ws  = (float*)d_ws;
    float* out = (float*)d_out;
    unsigned short* Bb1 = (unsigned short*)(ws + OFF_BB1);
    unsigned short* Bb2 = (unsigned short*)(ws + OFF_BB2);
    unsigned short* Y   = (unsigned short*)(ws + OFF_Y);

    hipLaunchKernelGGL(k_init, dim3((ZERO_END+255)/256), dim3(256), 0, stream, ws);
    hipLaunchKernelGGL(k_pool1_aux, dim3((N_NODES+255)/256), dim3(256), 0, stream,
                       pos, batch, cl1, ws);
    hipLaunchKernelGGL((k_swz<32>), dim3(104), dim3(256), 0, stream, n1w2, n1b2, Bb1);
    hipLaunchKernelGGL((k_swz<64>), dim3(208), dim3(256), 0, stream, n2w2, n2b2, Bb2);
    // conv1
    hipLaunchKernelGGL((k_phaseA<N_NODES, 832>), dim3(782), dim3(256), 0, stream,
                       x, Bb1, Y);
    hipLaunchKernelGGL((k_edge<32, 64>), dim3(N_EDGES/64), dim3(256), 0, stream,
                       Y, n1w1, n1b1, eidx, eidx + N_EDGES, ea, (const float*)nullptr,
                       ws + OFF_AGG1, 0);
    hipLaunchKernelGGL(k_conv1_final, dim3(N_NODES/8), dim3(256), 0, stream,
                       x, root1, bias1, cl1, ws);
    hipLaunchKernelGGL(k_pos2div, dim3((C1N*2+255)/256), dim3(256), 0, stream, ws);
    hipLaunchKernelGGL(k_cart1, dim3((N_EDGES+255)/256), dim3(256), 0, stream,
                       eidx, cl1, ws);
    // conv2
    hipLaunchKernelGGL((k_phaseA<C1N, 1664>), dim3(391), dim3(256), 0, stream,
                       ws + OFF_X2, Bb2, Y);
    hipLaunchKernelGGL((k_edge<64, 32>), dim3(N_EDGES/32), dim3(256), 0, stream,
                       Y, n2w1, n2b1, (const int*)(ws + OFF_ES), (const int*)(ws + OFF_ED),
                       ws + OFF_CART, ws + OFF_CMAX, ws + OFF_AGG2, 1);
    hipLaunchKernelGGL(k_conv2_final, dim3(C1N/4), dim3(256), 0, stream,
                       root2, bias2, cl2, ws);
    hipLaunchKernelGGL(k_gpool, dim3((C2N*64+255)/256), dim3(256), 0, stream, ws);
    hipLaunchKernelGGL(k_head, dim3(1), dim3(256), 0, stream,
                       fc1w, fc1b, fc2w, fc2b, ws, out);
}

// Round 8
// 461.390 us; speedup vs baseline: 2.0245x; 2.0245x over previous
//
#include <hip/hip_runtime.h>
#include <math.h>

#define N_NODES 50000
#define N_EDGES 160000
#define NB 32
#define C1N 25000
#define C2N 12500
#define EPB 64

// ---- workspace layout (in floats) ----
#define OFF_AGG1 0
#define SZ_AGG1 (N_NODES*32)
#define OFF_X2   (OFF_AGG1+SZ_AGG1)
#define SZ_X2    (C1N*32)
#define OFF_AGG2 (OFF_X2+SZ_X2)
#define SZ_AGG2  (C1N*64)
#define OFF_X4   (OFF_AGG2+SZ_AGG2)
#define SZ_X4    (C2N*64)
#define NEG_TOTAL (OFF_X4+SZ_X4)            // filled with -inf
#define OFF_P2S  NEG_TOTAL                  // pos2 sums  C1*2
#define OFF_CNT1 (OFF_P2S + C1N*2)          // counts     C1
#define OFF_GSUM (OFF_CNT1 + C1N)           // B*64
#define OFF_GCNT (OFF_GSUM + NB*64)         // B
#define OFF_CMAX (OFF_GCNT + NB)            // 1 (+3 pad)
#define OFF_B2I  (OFF_CMAX + 4)             // batch2 int C1
#define OFF_B3I  (OFF_B2I + C1N)            // batch3 int C2
#define ZERO_END (OFF_B3I + C2N)            // zero-filled up to here
#define OFF_POS2 (ZERO_END)                 // C1*2
#define OFF_ES   (OFF_POS2 + C1N*2)         // e2src int E
#define OFF_ED   (OFF_ES + N_EDGES)         // e2dst int E
#define OFF_CART (OFF_ED + N_EDGES)         // E*2
#define OFF_BB1  (OFF_CART + N_EDGES*2)     // 26*2*512 bf16 = 13312 floats
#define OFF_BB2  (OFF_BB1 + 13312)          // 26*4*512 bf16 = 26624 floats

typedef __attribute__((ext_vector_type(8))) short short8;
typedef __attribute__((ext_vector_type(4))) float f32x4;

__device__ __forceinline__ void atomicMaxFloat(float* addr, float v) {
    if (v >= 0.0f) atomicMax((int*)addr, __float_as_int(v + 0.0f)); // +0.0 canonicalizes -0
    else           atomicMin((unsigned int*)addr, __float_as_uint(v));
}
__device__ __forceinline__ float eluf(float v) { return v > 0.0f ? v : expm1f(v); }
__device__ __forceinline__ unsigned short f2bf(float f) {
    unsigned int u = __float_as_uint(f);
    u += 0x7FFFu + ((u >> 16) & 1u);   // round-to-nearest-even
    return (unsigned short)(u >> 16);
}

__global__ void k_init(float* ws) {
    int i = blockIdx.x*256 + threadIdx.x;
    if (i < ZERO_END) ws[i] = (i < NEG_TOTAL) ? -__builtin_inff() : 0.0f;
}

__global__ void k_pool1_aux(const float* __restrict__ pos, const int* __restrict__ batch,
                            const int* __restrict__ cl1, float* ws) {
    int n = blockIdx.x*256 + threadIdx.x;
    if (n >= N_NODES) return;
    int c = cl1[n];
    atomicAdd(&ws[OFF_P2S + c*2],     pos[n*2]);
    atomicAdd(&ws[OFF_P2S + c*2 + 1], pos[n*2+1]);
    atomicAdd(&ws[OFF_CNT1 + c], 1.0f);
    atomicMax((int*)(ws+OFF_B2I) + c, batch[n]);
}

// ---- build bf16 B-fragment bank for the [832 x O] GEMM.
// Bf[(h*(O/16)+ntg)*512 + l*8 + j] = W[h*32 + (l>>4)*8+j][ntg*16 + (l&15)]
// where W[kk][o]: rows kk=h*32+i; h<25 -> w2[h][i*O+o]; h==25 -> b2[i*O+o]
template<int O>
__global__ void k_swzf(const float* __restrict__ w2, const float* __restrict__ b2,
                       unsigned short* __restrict__ Bf) {
    const int TOT = 26*(O/16)*512;
    int idx = blockIdx.x*256 + threadIdx.x;
    if (idx >= TOT) return;
    int t = idx >> 9;
    int l = (idx >> 3) & 63, j = idx & 7;
    int h = t / (O/16), ntg = t % (O/16);
    int i = (l >> 4)*8 + j;
    int o = ntg*16 + (l & 15);
    float v = (h < 25) ? w2[h*(32*O) + i*O + o] : b2[i*O + o];
    Bf[idx] = f2bf(v);
}

// ---- edge phase as MFMA GEMM: [64 edges x 832] @ [832 x 32 cols/dispatch]
// z[e, h*32+i] = r[e,h]*x[src_e, i] formed in-register, W staged in LDS.
template<int O, int NTILES, int NTOFF_T, int SELF, int HASCM>
__global__ __launch_bounds__(256) void k_edgemm(
    const float* __restrict__ X, const unsigned short* __restrict__ Bf,
    const float* __restrict__ w1, const float* __restrict__ b1,
    const int* __restrict__ srcArr, const int* __restrict__ dstArr,
    const float* __restrict__ eaArr, const float* __restrict__ cmaxp,
    float* __restrict__ agg)
{
    __shared__ __align__(16) unsigned short Wl[26*NTILES*512];
    __shared__ float r_s[EPB][27];
    __shared__ int src_s[EPB], dst_s[EPB];
    int tid = threadIdx.x;
    int e0 = blockIdx.x * EPB;
    if (tid < EPB) { src_s[tid] = srcArr[e0+tid]; dst_s[tid] = dstArr[e0+tid]; }
    const int NU4 = 26*NTILES*64;      // uint4 chunks of Wl
    for (int idx = tid; idx < NU4; idx += 256) {
        int q = idx & 63, nt = (idx >> 6) % NTILES, h = idx / (64*NTILES);
        ((uint4*)Wl)[idx] = ((const uint4*)Bf)[(h*(O/16) + NTOFF_T + nt)*64 + q];
    }
    float sc = 1.0f, off = 0.0f;
    if (HASCM) { sc = 0.5f / *cmaxp; off = 0.5f; }
    for (int idx = tid; idx < EPB*25; idx += 256) {
        int e = idx / 25, h = idx - e*25;
        float a0 = eaArr[(e0+e)*2]   * sc + off;
        float a1 = eaArr[(e0+e)*2+1] * sc + off;
        r_s[e][h] = fmaxf(a0*w1[h] + a1*w1[25+h] + b1[h], 0.0f);
    }
    if (tid < EPB) r_s[tid][25] = 1.0f;
    __syncthreads();
    int l = tid & 63, w = tid >> 6;
    int erow = w*16 + (l & 15);
    int i0 = (l >> 4) * 8;
    const float* xr = X + (size_t)src_s[erow]*32 + i0;
    float xv[8];
    *(float4*)&xv[0] = *(const float4*)xr;
    *(float4*)&xv[4] = *(const float4*)(xr + 4);
    f32x4 acc[NTILES];
    #pragma unroll
    for (int nt = 0; nt < NTILES; ++nt) acc[nt] = (f32x4){0.f,0.f,0.f,0.f};
    for (int h = 0; h < 26; ++h) {
        float rv = r_s[erow][h];
        union { short8 s8; unsigned int u[4]; } av;
        #pragma unroll
        for (int p = 0; p < 4; ++p) {
            float lo = xv[2*p]   * rv;
            float hi = xv[2*p+1] * rv;
            asm("v_cvt_pk_bf16_f32 %0, %1, %2" : "=v"(av.u[p]) : "v"(lo), "v"(hi));
        }
        #pragma unroll
        for (int nt = 0; nt < NTILES; ++nt) {
            short8 bv = *(const short8*)&Wl[(h*NTILES + nt)*512 + l*8];
            acc[nt] = __builtin_amdgcn_mfma_f32_16x16x32_bf16(av.s8, bv, acc[nt], 0, 0, 0);
        }
    }
    int colb = NTOFF_T*16 + (l & 15);
    #pragma unroll
    for (int nt = 0; nt < NTILES; ++nt) {
        #pragma unroll
        for (int r = 0; r < 4; ++r) {
            int er = w*16 + (l >> 4)*4 + r;
            int d = dst_s[er];
            if (!SELF || src_s[er] != d)
                atomicMaxFloat(&agg[(size_t)d*O + colb + nt*16], acc[nt][r]);
        }
    }
}

__global__ void k_conv1_final(const float* __restrict__ x, const float* __restrict__ root1,
                              const float* __restrict__ bias1, const int* __restrict__ cl1,
                              float* ws) {
    __shared__ float xs[256];
    int tid = threadIdx.x;
    int n0 = blockIdx.x*8;                       // 50000 = 8*6250 exact
    xs[tid] = x[(n0 + (tid>>5))*32 + (tid&31)];
    __syncthreads();
    int n = n0 + (tid>>5), o = tid & 31;
    float v = ws[OFF_AGG1 + n*32 + o];
    if (v == -__builtin_inff()) v = 0.0f;
    float acc = bias1[o];
    const float* xr = xs + (tid>>5)*32;
    #pragma unroll
    for (int i = 0; i < 32; ++i) acc += xr[i]*root1[i*32+o];
    v = eluf(v + acc);
    atomicMaxFloat(&ws[OFF_X2 + cl1[n]*32 + o], v);
}

__global__ void k_pos2div(float* ws) {
    int i = blockIdx.x*256 + threadIdx.x;
    if (i >= C1N*2) return;
    int c = i >> 1;
    ws[OFF_POS2 + i] = ws[OFF_P2S + i] / fmaxf(ws[OFF_CNT1 + c], 1.0f);
}

__global__ void k_cart1(const int* __restrict__ eidx, const int* __restrict__ cl1,
                        float* ws) {
    int e = blockIdx.x*256 + threadIdx.x;
    float m = 0.0f;
    if (e < N_EDGES) {
        int s = cl1[eidx[e]], d = cl1[eidx[N_EDGES+e]];
        ((int*)(ws+OFF_ES))[e] = s;
        ((int*)(ws+OFF_ED))[e] = d;
        float cx = ws[OFF_POS2 + d*2]     - ws[OFF_POS2 + s*2];
        float cy = ws[OFF_POS2 + d*2 + 1] - ws[OFF_POS2 + s*2 + 1];
        ws[OFF_CART + e*2] = cx; ws[OFF_CART + e*2 + 1] = cy;
        m = fmaxf(fabsf(cx), fabsf(cy));
    }
    #pragma unroll
    for (int off = 32; off; off >>= 1) m = fmaxf(m, __shfl_xor(m, off));
    if ((threadIdx.x & 63) == 0) atomicMax((int*)(ws+OFF_CMAX), __float_as_int(m));
}

__global__ void k_conv2_final(const float* __restrict__ root2, const float* __restrict__ bias2,
                              const int* __restrict__ cl2, float* ws) {
    __shared__ float xs[128];
    int tid = threadIdx.x;
    int c0 = blockIdx.x*4;                       // 25000 = 4*6250 exact
    if (tid < 128) xs[tid] = ws[OFF_X2 + (c0 + (tid>>5))*32 + (tid&31)];
    __syncthreads();
    int c = c0 + (tid>>6), o = tid & 63;
    float v = ws[OFF_AGG2 + c*64 + o];
    if (v == -__builtin_inff()) v = 0.0f;
    float acc = bias2[o];
    const float* xr = xs + (tid>>6)*32;
    #pragma unroll
    for (int i = 0; i < 32; ++i) acc += xr[i]*root2[i*64+o];
    v = eluf(v + acc);
    int c2 = cl2[c];
    atomicMaxFloat(&ws[OFF_X4 + c2*64 + o], v);
    if (o == 0) atomicMax((int*)(ws+OFF_B3I) + c2, ((int*)(ws+OFF_B2I))[c]);
}

__global__ void k_gpool(float* ws) {
    int idx = blockIdx.x*256 + threadIdx.x;
    if (idx >= C2N*64) return;
    int c = idx >> 6, o = idx & 63;
    float v = ws[OFF_X4 + idx];
    if (v == -__builtin_inff()) v = 0.0f;
    int b = ((int*)(ws+OFF_B3I))[c];
    atomicAdd(&ws[OFF_GSUM + b*64 + o], v);
    if (o == 0) atomicAdd(&ws[OFF_GCNT + b], 1.0f);
}

__global__ __launch_bounds__(256) void k_head(
    const float* __restrict__ fc1w, const float* __restrict__ fc1b,
    const float* __restrict__ fc2w, const float* __restrict__ fc2b,
    const float* __restrict__ ws, float* __restrict__ out) {
    __shared__ float g_s[32*64], h_s[32*128], l_s[32*32];
    int tid = threadIdx.x;
    for (int idx = tid; idx < 32*64; idx += 256) {
        int b = idx >> 6;
        g_s[idx] = ws[OFF_GSUM + idx] / fmaxf(ws[OFF_GCNT + b], 1.0f);
    }
    __syncthreads();
    for (int idx = tid; idx < 32*128; idx += 256) {
        int b = idx >> 7, f = idx & 127;
        float a = fc1b[f];
        #pragma unroll 8
        for (int i = 0; i < 64; ++i) a += g_s[b*64+i]*fc1w[i*128+f];
        h_s[idx] = eluf(a);
    }
    __syncthreads();
    for (int idx = tid; idx < 32*32; idx += 256) {
        int b = idx >> 5, o = idx & 31;
        float a = fc2b[o];
        #pragma unroll 8
        for (int i = 0; i < 128; ++i) a += h_s[b*128+i]*fc2w[i*32+o];
        l_s[idx] = a;
    }
    __syncthreads();
    if (tid < 32) {
        int b = tid;
        float m = -__builtin_inff();
        for (int o = 0; o < 32; ++o) m = fmaxf(m, l_s[b*32+o]);
        float s = 0.0f;
        for (int o = 0; o < 32; ++o) s += expf(l_s[b*32+o]-m);
        float lg = logf(s);
        for (int o = 0; o < 32; ++o) out[b*32+o] = l_s[b*32+o]-m-lg;
    }
}

extern "C" void kernel_launch(void* const* d_in, const int* in_sizes, int n_in,
                              void* d_out, int out_size, void* d_ws, size_t ws_size,
                              hipStream_t stream) {
    const float* x    = (const float*)d_in[0];
    const float* pos  = (const float*)d_in[1];
    const float* ea   = (const float*)d_in[2];
    const int*   eidx = (const int*)  d_in[3];
    const int*   batch= (const int*)  d_in[4];
    const int*   cl1  = (const int*)  d_in[5];
    const int*   cl2  = (const int*)  d_in[6];
    const float* n1w1 = (const float*)d_in[7];
    const float* n1b1 = (const float*)d_in[8];
    const float* n1w2 = (const float*)d_in[9];
    const float* n1b2 = (const float*)d_in[10];
    const float* root1= (const float*)d_in[11];
    const float* bias1= (const float*)d_in[12];
    const float* n2w1 = (const float*)d_in[13];
    const float* n2b1 = (const float*)d_in[14];
    const float* n2w2 = (const float*)d_in[15];
    const float* n2b2 = (const float*)d_in[16];
    const float* root2= (const float*)d_in[17];
    const float* bias2= (const float*)d_in[18];
    const float* fc1w = (const float*)d_in[19];
    const float* fc1b = (const float*)d_in[20];
    const float* fc2w = (const float*)d_in[21];
    const float* fc2b = (const float*)d_in[22];
    float* ws  = (float*)d_ws;
    float* out = (float*)d_out;
    unsigned short* Bb1 = (unsigned short*)(ws + OFF_BB1);
    unsigned short* Bb2 = (unsigned short*)(ws + OFF_BB2);

    hipLaunchKernelGGL(k_init, dim3((ZERO_END+255)/256), dim3(256), 0, stream, ws);
    hipLaunchKernelGGL(k_pool1_aux, dim3((N_NODES+255)/256), dim3(256), 0, stream,
                       pos, batch, cl1, ws);
    hipLaunchKernelGGL((k_swzf<32>), dim3(104), dim3(256), 0, stream, n1w2, n1b2, Bb1);
    hipLaunchKernelGGL((k_swzf<64>), dim3(208), dim3(256), 0, stream, n2w2, n2b2, Bb2);
    // conv1: [E x 832] @ [832 x 32], all 32 cols in one dispatch
    hipLaunchKernelGGL((k_edgemm<32, 2, 0, 0, 0>), dim3(N_EDGES/EPB), dim3(256), 0, stream,
                       x, Bb1, n1w1, n1b1, eidx, eidx + N_EDGES, ea,
                       (const float*)nullptr, ws + OFF_AGG1);
    hipLaunchKernelGGL(k_conv1_final, dim3(N_NODES/8), dim3(256), 0, stream,
                       x, root1, bias1, cl1, ws);
    hipLaunchKernelGGL(k_pos2div, dim3((C1N*2+255)/256), dim3(256), 0, stream, ws);
    hipLaunchKernelGGL(k_cart1, dim3((N_EDGES+255)/256), dim3(256), 0, stream,
                       eidx, cl1, ws);
    // conv2: [E x 832] @ [832 x 64], two dispatches of 32 cols (LDS budget)
    hipLaunchKernelGGL((k_edgemm<64, 2, 0, 1, 1>), dim3(N_EDGES/EPB), dim3(256), 0, stream,
                       ws + OFF_X2, Bb2, n2w1, n2b1,
                       (const int*)(ws + OFF_ES), (const int*)(ws + OFF_ED),
                       ws + OFF_CART, ws + OFF_CMAX, ws + OFF_AGG2);
    hipLaunchKernelGGL((k_edgemm<64, 2, 2, 1, 1>), dim3(N_EDGES/EPB), dim3(256), 0, stream,
                       ws + OFF_X2, Bb2, n2w1, n2b1,
                       (const int*)(ws + OFF_ES), (const int*)(ws + OFF_ED),
                       ws + OFF_CART, ws + OFF_CMAX, ws + OFF_AGG2);
    hipLaunchKernelGGL(k_conv2_final, dim3(C1N/4), dim3(256), 0, stream,
                       root2, bias2, cl2, ws);
    hipLaunchKernelGGL(k_gpool, dim3((C2N*64+255)/256), dim3(256), 0, stream, ws);
    hipLaunchKernelGGL(k_head, dim3(1), dim3(256), 0, stream,
                       fc1w, fc1b, fc2w, fc2b, ws, out);
}

// Round 9
// 374.469 us; speedup vs baseline: 2.4944x; 1.2321x over previous
//
#include <hip/hip_runtime.h>
#include <math.h>

#define N_NODES 50000
#define N_EDGES 160000
#define NB 32
#define C1N 25000
#define C2N 12500
#define EPB 64
#define GPB 128

// ---- workspace layout (in floats) ----
#define OFF_AGG1 0
#define SZ_AGG1 (N_NODES*32)
#define OFF_X2   (OFF_AGG1+SZ_AGG1)
#define SZ_X2    (C1N*32)
#define OFF_AGG2 (OFF_X2+SZ_X2)
#define SZ_AGG2  (C1N*64)
#define OFF_X4   (OFF_AGG2+SZ_AGG2)
#define SZ_X4    (C2N*64)
#define NEG_TOTAL (OFF_X4+SZ_X4)            // filled with -inf
#define OFF_P2S  NEG_TOTAL                  // pos2 sums  C1*2
#define OFF_CNT1 (OFF_P2S + C1N*2)          // counts     C1
#define OFF_GSUM (OFF_CNT1 + C1N)           // B*64
#define OFF_GCNT (OFF_GSUM + NB*64)         // B
#define OFF_CMAX (OFF_GCNT + NB)            // 1 (+3 pad)
#define OFF_B2I  (OFF_CMAX + 4)             // batch2 int C1
#define OFF_B3I  (OFF_B2I + C1N)            // batch3 int C2
#define ZERO_END (OFF_B3I + C2N)            // zero-filled up to here
#define OFF_POS2 (ZERO_END)                 // C1*2
#define OFF_ES   (OFF_POS2 + C1N*2)         // e2src int E
#define OFF_ED   (OFF_ES + N_EDGES)         // e2dst int E
#define OFF_CART (OFF_ED + N_EDGES)         // E*2
#define OFF_BB1  (OFF_CART + N_EDGES*2)     // 26*2*512 bf16 = 13312 floats
#define OFF_BB2  (OFF_BB1 + 13312)          // 26*4*512 bf16 = 26624 floats

typedef __attribute__((ext_vector_type(8))) short short8;
typedef __attribute__((ext_vector_type(4))) float f32x4;

__device__ __forceinline__ void atomicMaxFloat(float* addr, float v) {
    if (v >= 0.0f) atomicMax((int*)addr, __float_as_int(v + 0.0f)); // +0.0 canonicalizes -0
    else           atomicMin((unsigned int*)addr, __float_as_uint(v));
}
__device__ __forceinline__ float eluf(float v) { return v > 0.0f ? v : expm1f(v); }
__device__ __forceinline__ unsigned short f2bf(float f) {
    unsigned int u = __float_as_uint(f);
    u += 0x7FFFu + ((u >> 16) & 1u);   // round-to-nearest-even
    return (unsigned short)(u >> 16);
}

__global__ void k_init(float* ws) {
    int i = blockIdx.x*256 + threadIdx.x;
    if (i < ZERO_END) ws[i] = (i < NEG_TOTAL) ? -__builtin_inff() : 0.0f;
}

__global__ void k_pool1_aux(const float* __restrict__ pos, const int* __restrict__ batch,
                            const int* __restrict__ cl1, float* ws) {
    int n = blockIdx.x*256 + threadIdx.x;
    if (n >= N_NODES) return;
    int c = cl1[n];
    atomicAdd(&ws[OFF_P2S + c*2],     pos[n*2]);
    atomicAdd(&ws[OFF_P2S + c*2 + 1], pos[n*2+1]);
    atomicAdd(&ws[OFF_CNT1 + c], 1.0f);
    atomicMax((int*)(ws+OFF_B2I) + c, batch[n]);
}

// ---- build bf16 B-fragment bank for the [832 x O] GEMM.
// Bf[(h*(O/16)+ntg)*512 + l*8 + j] = W[h*32 + (l>>4)*8+j][ntg*16 + (l&15)]
// where W[kk][o]: rows kk=h*32+i; h<25 -> w2[h][i*O+o]; h==25 -> b2[i*O+o]
template<int O>
__global__ void k_swzf(const float* __restrict__ w2, const float* __restrict__ b2,
                       unsigned short* __restrict__ Bf) {
    const int TOT = 26*(O/16)*512;
    int idx = blockIdx.x*256 + threadIdx.x;
    if (idx >= TOT) return;
    int t = idx >> 9;
    int l = (idx >> 3) & 63, j = idx & 7;
    int h = t / (O/16), ntg = t % (O/16);
    int i = (l >> 4)*8 + j;
    int o = ntg*16 + (l & 15);
    float v = (h < 25) ? w2[h*(32*O) + i*O + o] : b2[i*O + o];
    Bf[idx] = f2bf(v);
}

// ---- edge phase as MFMA GEMM: [64 edges x 832] @ [832 x 32 cols/dispatch]
// z[e, h*32+i] = r[e,h]*x[src_e, i] formed in-register, W staged in LDS.
template<int O, int NTILES, int NTOFF_T, int SELF, int HASCM>
__global__ __launch_bounds__(256) void k_edgemm(
    const float* __restrict__ X, const unsigned short* __restrict__ Bf,
    const float* __restrict__ w1, const float* __restrict__ b1,
    const int* __restrict__ srcArr, const int* __restrict__ dstArr,
    const float* __restrict__ eaArr, const float* __restrict__ cmaxp,
    float* __restrict__ agg)
{
    __shared__ __align__(16) unsigned short Wl[26*NTILES*512];
    __shared__ float r_s[EPB][27];
    __shared__ int src_s[EPB], dst_s[EPB];
    int tid = threadIdx.x;
    int e0 = blockIdx.x * EPB;
    if (tid < EPB) { src_s[tid] = srcArr[e0+tid]; dst_s[tid] = dstArr[e0+tid]; }
    const int NU4 = 26*NTILES*64;      // uint4 chunks of Wl
    for (int idx = tid; idx < NU4; idx += 256) {
        int q = idx & 63, nt = (idx >> 6) % NTILES, h = idx / (64*NTILES);
        ((uint4*)Wl)[idx] = ((const uint4*)Bf)[(h*(O/16) + NTOFF_T + nt)*64 + q];
    }
    float sc = 1.0f, off = 0.0f;
    if (HASCM) { sc = 0.5f / *cmaxp; off = 0.5f; }
    for (int idx = tid; idx < EPB*25; idx += 256) {
        int e = idx / 25, h = idx - e*25;
        float a0 = eaArr[(e0+e)*2]   * sc + off;
        float a1 = eaArr[(e0+e)*2+1] * sc + off;
        r_s[e][h] = fmaxf(a0*w1[h] + a1*w1[25+h] + b1[h], 0.0f);
    }
    if (tid < EPB) r_s[tid][25] = 1.0f;
    __syncthreads();
    int l = tid & 63, w = tid >> 6;
    int erow = w*16 + (l & 15);
    int i0 = (l >> 4) * 8;
    const float* xr = X + (size_t)src_s[erow]*32 + i0;
    float xv[8];
    *(float4*)&xv[0] = *(const float4*)xr;
    *(float4*)&xv[4] = *(const float4*)(xr + 4);
    f32x4 acc[NTILES];
    #pragma unroll
    for (int nt = 0; nt < NTILES; ++nt) acc[nt] = (f32x4){0.f,0.f,0.f,0.f};
    for (int h = 0; h < 26; ++h) {
        float rv = r_s[erow][h];
        union { short8 s8; unsigned int u[4]; } av;
        #pragma unroll
        for (int p = 0; p < 4; ++p) {
            float lo = xv[2*p]   * rv;
            float hi = xv[2*p+1] * rv;
            asm("v_cvt_pk_bf16_f32 %0, %1, %2" : "=v"(av.u[p]) : "v"(lo), "v"(hi));
        }
        #pragma unroll
        for (int nt = 0; nt < NTILES; ++nt) {
            short8 bv = *(const short8*)&Wl[(h*NTILES + nt)*512 + l*8];
            acc[nt] = __builtin_amdgcn_mfma_f32_16x16x32_bf16(av.s8, bv, acc[nt], 0, 0, 0);
        }
    }
    int colb = NTOFF_T*16 + (l & 15);
    #pragma unroll
    for (int nt = 0; nt < NTILES; ++nt) {
        #pragma unroll
        for (int r = 0; r < 4; ++r) {
            int er = w*16 + (l >> 4)*4 + r;
            int d = dst_s[er];
            if (!SELF || src_s[er] != d)
                atomicMaxFloat(&agg[(size_t)d*O + colb + nt*16], acc[nt][r]);
        }
    }
}

__global__ void k_conv1_final(const float* __restrict__ x, const float* __restrict__ root1,
                              const float* __restrict__ bias1, const int* __restrict__ cl1,
                              float* ws) {
    __shared__ float xs[256];
    int tid = threadIdx.x;
    int n0 = blockIdx.x*8;                       // 50000 = 8*6250 exact
    xs[tid] = x[(n0 + (tid>>5))*32 + (tid&31)];
    __syncthreads();
    int n = n0 + (tid>>5), o = tid & 31;
    float v = ws[OFF_AGG1 + n*32 + o];
    if (v == -__builtin_inff()) v = 0.0f;
    float acc = bias1[o];
    const float* xr = xs + (tid>>5)*32;
    #pragma unroll
    for (int i = 0; i < 32; ++i) acc += xr[i]*root1[i*32+o];
    v = eluf(v + acc);
    atomicMaxFloat(&ws[OFF_X2 + cl1[n]*32 + o], v);
}

__global__ void k_pos2div(float* ws) {
    int i = blockIdx.x*256 + threadIdx.x;
    if (i >= C1N*2) return;
    int c = i >> 1;
    ws[OFF_POS2 + i] = ws[OFF_P2S + i] / fmaxf(ws[OFF_CNT1 + c], 1.0f);
}

__global__ void k_cart1(const int* __restrict__ eidx, const int* __restrict__ cl1,
                        float* ws) {
    int e = blockIdx.x*256 + threadIdx.x;
    float m = 0.0f;
    if (e < N_EDGES) {
        int s = cl1[eidx[e]], d = cl1[eidx[N_EDGES+e]];
        ((int*)(ws+OFF_ES))[e] = s;
        ((int*)(ws+OFF_ED))[e] = d;
        float cx = ws[OFF_POS2 + d*2]     - ws[OFF_POS2 + s*2];
        float cy = ws[OFF_POS2 + d*2 + 1] - ws[OFF_POS2 + s*2 + 1];
        ws[OFF_CART + e*2] = cx; ws[OFF_CART + e*2 + 1] = cy;
        m = fmaxf(fabsf(cx), fabsf(cy));
    }
    #pragma unroll
    for (int off = 32; off; off >>= 1) m = fmaxf(m, __shfl_xor(m, off));
    if ((threadIdx.x & 63) == 0) atomicMax((int*)(ws+OFF_CMAX), __float_as_int(m));
}

__global__ void k_conv2_final(const float* __restrict__ root2, const float* __restrict__ bias2,
                              const int* __restrict__ cl2, float* ws) {
    __shared__ float xs[128];
    int tid = threadIdx.x;
    int c0 = blockIdx.x*4;                       // 25000 = 4*6250 exact
    if (tid < 128) xs[tid] = ws[OFF_X2 + (c0 + (tid>>5))*32 + (tid&31)];
    __syncthreads();
    int c = c0 + (tid>>6), o = tid & 63;
    float v = ws[OFF_AGG2 + c*64 + o];
    if (v == -__builtin_inff()) v = 0.0f;
    float acc = bias2[o];
    const float* xr = xs + (tid>>6)*32;
    #pragma unroll
    for (int i = 0; i < 32; ++i) acc += xr[i]*root2[i*64+o];
    v = eluf(v + acc);
    int c2 = cl2[c];
    atomicMaxFloat(&ws[OFF_X4 + c2*64 + o], v);
    if (o == 0) atomicMax((int*)(ws+OFF_B3I) + c2, ((int*)(ws+OFF_B2I))[c]);
}

// ---- global mean pool: run-length pre-aggregation over monotone batch3
__global__ __launch_bounds__(256) void k_gpool(float* ws) {
    int tid = threadIdx.x;
    int o = tid & 63, cl = tid >> 6;
    const int CPB = (C2N + GPB - 1) / GPB;       // 98
    int c0 = blockIdx.x * CPB;
    int c1 = c0 + CPB; if (c1 > C2N) c1 = C2N;
    const int* b3 = (const int*)(ws + OFF_B3I);
    float acc = 0.0f, cnt = 0.0f;
    int curb = -1;
    for (int c = c0 + cl; c < c1; c += 4) {
        int b = b3[c];
        float v = ws[OFF_X4 + c*64 + o];
        if (v == -__builtin_inff()) v = 0.0f;
        if (b != curb) {
            if (curb >= 0) {
                atomicAdd(&ws[OFF_GSUM + curb*64 + o], acc);
                if (o == 0) atomicAdd(&ws[OFF_GCNT + curb], cnt);
            }
            curb = b; acc = 0.0f; cnt = 0.0f;
        }
        acc += v; cnt += 1.0f;
    }
    if (curb >= 0) {
        atomicAdd(&ws[OFF_GSUM + curb*64 + o], acc);
        if (o == 0) atomicAdd(&ws[OFF_GCNT + curb], cnt);
    }
}

__global__ __launch_bounds__(256) void k_head(
    const float* __restrict__ fc1w, const float* __restrict__ fc1b,
    const float* __restrict__ fc2w, const float* __restrict__ fc2b,
    const float* __restrict__ ws, float* __restrict__ out) {
    __shared__ float g_s[32*64], h_s[32*128], l_s[32*32];
    int tid = threadIdx.x;
    for (int idx = tid; idx < 32*64; idx += 256) {
        int b = idx >> 6;
        g_s[idx] = ws[OFF_GSUM + idx] / fmaxf(ws[OFF_GCNT + b], 1.0f);
    }
    __syncthreads();
    for (int idx = tid; idx < 32*128; idx += 256) {
        int b = idx >> 7, f = idx & 127;
        float a = fc1b[f];
        #pragma unroll 8
        for (int i = 0; i < 64; ++i) a += g_s[b*64+i]*fc1w[i*128+f];
        h_s[idx] = eluf(a);
    }
    __syncthreads();
    for (int idx = tid; idx < 32*32; idx += 256) {
        int b = idx >> 5, o = idx & 31;
        float a = fc2b[o];
        #pragma unroll 8
        for (int i = 0; i < 128; ++i) a += h_s[b*128+i]*fc2w[i*32+o];
        l_s[idx] = a;
    }
    __syncthreads();
    if (tid < 32) {
        int b = tid;
        float m = -__builtin_inff();
        for (int o = 0; o < 32; ++o) m = fmaxf(m, l_s[b*32+o]);
        float s = 0.0f;
        for (int o = 0; o < 32; ++o) s += expf(l_s[b*32+o]-m);
        float lg = logf(s);
        for (int o = 0; o < 32; ++o) out[b*32+o] = l_s[b*32+o]-m-lg;
    }
}

extern "C" void kernel_launch(void* const* d_in, const int* in_sizes, int n_in,
                              void* d_out, int out_size, void* d_ws, size_t ws_size,
                              hipStream_t stream) {
    const float* x    = (const float*)d_in[0];
    const float* pos  = (const float*)d_in[1];
    const float* ea   = (const float*)d_in[2];
    const int*   eidx = (const int*)  d_in[3];
    const int*   batch= (const int*)  d_in[4];
    const int*   cl1  = (const int*)  d_in[5];
    const int*   cl2  = (const int*)  d_in[6];
    const float* n1w1 = (const float*)d_in[7];
    const float* n1b1 = (const float*)d_in[8];
    const float* n1w2 = (const float*)d_in[9];
    const float* n1b2 = (const float*)d_in[10];
    const float* root1= (const float*)d_in[11];
    const float* bias1= (const float*)d_in[12];
    const float* n2w1 = (const float*)d_in[13];
    const float* n2b1 = (const float*)d_in[14];
    const float* n2w2 = (const float*)d_in[15];
    const float* n2b2 = (const float*)d_in[16];
    const float* root2= (const float*)d_in[17];
    const float* bias2= (const float*)d_in[18];
    const float* fc1w = (const float*)d_in[19];
    const float* fc1b = (const float*)d_in[20];
    const float* fc2w = (const float*)d_in[21];
    const float* fc2b = (const float*)d_in[22];
    float* ws  = (float*)d_ws;
    float* out = (float*)d_out;
    unsigned short* Bb1 = (unsigned short*)(ws + OFF_BB1);
    unsigned short* Bb2 = (unsigned short*)(ws + OFF_BB2);

    hipLaunchKernelGGL(k_init, dim3((ZERO_END+255)/256), dim3(256), 0, stream, ws);
    hipLaunchKernelGGL(k_pool1_aux, dim3((N_NODES+255)/256), dim3(256), 0, stream,
                       pos, batch, cl1, ws);
    hipLaunchKernelGGL((k_swzf<32>), dim3(104), dim3(256), 0, stream, n1w2, n1b2, Bb1);
    hipLaunchKernelGGL((k_swzf<64>), dim3(208), dim3(256), 0, stream, n2w2, n2b2, Bb2);
    // conv1: [E x 832] @ [832 x 32], all 32 cols in one dispatch
    hipLaunchKernelGGL((k_edgemm<32, 2, 0, 0, 0>), dim3(N_EDGES/EPB), dim3(256), 0, stream,
                       x, Bb1, n1w1, n1b1, eidx, eidx + N_EDGES, ea,
                       (const float*)nullptr, ws + OFF_AGG1);
    hipLaunchKernelGGL(k_conv1_final, dim3(N_NODES/8), dim3(256), 0, stream,
                       x, root1, bias1, cl1, ws);
    hipLaunchKernelGGL(k_pos2div, dim3((C1N*2+255)/256), dim3(256), 0, stream, ws);
    hipLaunchKernelGGL(k_cart1, dim3((N_EDGES+255)/256), dim3(256), 0, stream,
                       eidx, cl1, ws);
    // conv2: [E x 832] @ [832 x 64], two dispatches of 32 cols (LDS budget)
    hipLaunchKernelGGL((k_edgemm<64, 2, 0, 1, 1>), dim3(N_EDGES/EPB), dim3(256), 0, stream,
                       ws + OFF_X2, Bb2, n2w1, n2b1,
                       (const int*)(ws + OFF_ES), (const int*)(ws + OFF_ED),
                       ws + OFF_CART, ws + OFF_CMAX, ws + OFF_AGG2);
    hipLaunchKernelGGL((k_edgemm<64, 2, 2, 1, 1>), dim3(N_EDGES/EPB), dim3(256), 0, stream,
                       ws + OFF_X2, Bb2, n2w1, n2b1,
                       (const int*)(ws + OFF_ES), (const int*)(ws + OFF_ED),
                       ws + OFF_CART, ws + OFF_CMAX, ws + OFF_AGG2);
    hipLaunchKernelGGL(k_conv2_final, dim3(C1N/4), dim3(256), 0, stream,
                       root2, bias2, cl2, ws);
    hipLaunchKernelGGL(k_gpool, dim3(GPB), dim3(256), 0, stream, ws);
    hipLaunchKernelGGL(k_head, dim3(1), dim3(256), 0, stream,
                       fc1w, fc1b, fc2w, fc2b, ws, out);
}

// Round 10
// 307.767 us; speedup vs baseline: 3.0351x; 1.2167x over previous
//
#include <hip/hip_runtime.h>
#include <math.h>

#define N_NODES 50000
#define N_EDGES 160000
#define NB 32
#define C1N 25000
#define C2N 12500
#define EPB 128
#define GPB 128

// ---- workspace layout (in floats) ----
#define OFF_AGG1 0
#define SZ_AGG1 (N_NODES*32)
#define OFF_AGG2 (OFF_AGG1+SZ_AGG1)
#define SZ_AGG2  (C1N*64)
#define NEG_TOTAL (OFF_AGG2+SZ_AGG2)        // [0,NEG_TOTAL) = -inf
#define OFF_GSUM NEG_TOTAL                  // B*64 (zeroed)
#define OFF_GCNT (OFF_GSUM + NB*64)         // B
#define OFF_CMAX (OFF_GCNT + NB)            // 1 (+3 pad)
#define ZERO_END (OFF_CMAX + 4)
#define OFF_X2   ZERO_END                   // C1*32 (written direct)
#define OFF_POS2 (OFF_X2 + C1N*32)          // C1*2
#define OFF_X4   (OFF_POS2 + C1N*2)         // C2*64 (written direct)
#define OFF_CART (OFF_X4 + C2N*64)          // E*2
#define OFF_BB1  (OFF_CART + N_EDGES*2)     // 26*2*512 bf16 = 13312 floats
#define OFF_BB2  (OFF_BB1 + 13312)          // 26*4*512 bf16 = 26624 floats

typedef __attribute__((ext_vector_type(8))) short short8;
typedef __attribute__((ext_vector_type(4))) float f32x4;

__device__ __forceinline__ void atomicMaxFloat(float* addr, float v) {
    if (v >= 0.0f) atomicMax((int*)addr, __float_as_int(v + 0.0f)); // +0.0 canonicalizes -0
    else           atomicMin((unsigned int*)addr, __float_as_uint(v));
}
__device__ __forceinline__ float eluf(float v) { return v > 0.0f ? v : expm1f(v); }
__device__ __forceinline__ unsigned short f2bf(float f) {
    unsigned int u = __float_as_uint(f);
    u += 0x7FFFu + ((u >> 16) & 1u);   // round-to-nearest-even
    return (unsigned short)(u >> 16);
}

__global__ void k_init(float* ws) {
    int i = blockIdx.x*256 + threadIdx.x;
    if (i < ZERO_END) ws[i] = (i < NEG_TOTAL) ? -__builtin_inff() : 0.0f;
}

// ---- build bf16 B-fragment bank for the [832 x O] GEMM.
// Bf[(h*(O/16)+ntg)*512 + l*8 + j] = W[h*32 + (l>>4)*8+j][ntg*16 + (l&15)]
// W[kk][o]: rows kk=h*32+i; h<25 -> w2[h][i*O+o]; h==25 -> b2[i*O+o]
template<int O>
__global__ void k_swzf(const float* __restrict__ w2, const float* __restrict__ b2,
                       unsigned short* __restrict__ Bf) {
    const int TOT = 26*(O/16)*512;
    int idx = blockIdx.x*256 + threadIdx.x;
    if (idx >= TOT) return;
    int t = idx >> 9;
    int l = (idx >> 3) & 63, j = idx & 7;
    int h = t / (O/16), ntg = t % (O/16);
    int i = (l >> 4)*8 + j;
    int o = ntg*16 + (l & 15);
    float v = (h < 25) ? w2[h*(32*O) + i*O + o] : b2[i*O + o];
    Bf[idx] = f2bf(v);
}

// ---- edge phase as MFMA GEMM: [128 edges x 832] @ [832 x 32 cols/dispatch]
// z[e, h*32+i] = r[e,h]*x[src_e, i]; r computed in-register per lane;
// W staged in LDS, shared by 8 waves.
template<int O, int NTILES, int NTOFF_T, int SELF, int HASCM, int SHIFT>
__global__ __launch_bounds__(512, 4) void k_edgemm(
    const float* __restrict__ X, const unsigned short* __restrict__ Bf,
    const float* __restrict__ w1, const float* __restrict__ b1,
    const int* __restrict__ srcArr, const int* __restrict__ dstArr,
    const float* __restrict__ eaArr, const float* __restrict__ cmaxp,
    float* __restrict__ agg)
{
    __shared__ __align__(16) unsigned short Wl[26*NTILES*512];
    __shared__ int src_s[EPB], dst_s[EPB];
    int tid = threadIdx.x;
    int e0 = blockIdx.x * EPB;
    if (tid < EPB) {
        int s = srcArr[e0+tid], d = dstArr[e0+tid];
        if (SHIFT) { s >>= 1; d >>= 1; }
        src_s[tid] = s; dst_s[tid] = d;
    }
    const int NU4 = 26*NTILES*64;      // uint4 chunks of Wl
    for (int idx = tid; idx < NU4; idx += 512) {
        int q = idx & 63, nt = (idx >> 6) % NTILES, h = idx / (64*NTILES);
        ((uint4*)Wl)[idx] = ((const uint4*)Bf)[(h*(O/16) + NTOFF_T + nt)*64 + q];
    }
    float sc = 1.0f, off = 0.0f;
    if (HASCM) { sc = 0.5f / *cmaxp; off = 0.5f; }
    int l = tid & 63, w = tid >> 6;
    int erow = w*16 + (l & 15);
    int i0 = (l >> 4) * 8;
    int e = e0 + erow;
    float a0 = eaArr[e*2]   * sc + off;
    float a1 = eaArr[e*2+1] * sc + off;
    __syncthreads();
    const float* xr = X + (size_t)src_s[erow]*32 + i0;
    float xv[8];
    *(float4*)&xv[0] = *(const float4*)xr;
    *(float4*)&xv[4] = *(const float4*)(xr + 4);
    f32x4 acc[NTILES];
    #pragma unroll
    for (int nt = 0; nt < NTILES; ++nt) acc[nt] = (f32x4){0.f,0.f,0.f,0.f};
    for (int h = 0; h < 26; ++h) {
        float rv = (h < 25) ? fmaxf(a0*w1[h] + a1*w1[25+h] + b1[h], 0.0f) : 1.0f;
        union { short8 s8; unsigned int u[4]; } av;
        #pragma unroll
        for (int p = 0; p < 4; ++p) {
            float lo = xv[2*p]   * rv;
            float hi = xv[2*p+1] * rv;
            asm("v_cvt_pk_bf16_f32 %0, %1, %2" : "=v"(av.u[p]) : "v"(lo), "v"(hi));
        }
        #pragma unroll
        for (int nt = 0; nt < NTILES; ++nt) {
            short8 bv = *(const short8*)&Wl[(h*NTILES + nt)*512 + l*8];
            acc[nt] = __builtin_amdgcn_mfma_f32_16x16x32_bf16(av.s8, bv, acc[nt], 0, 0, 0);
        }
    }
    int colb = NTOFF_T*16 + (l & 15);
    #pragma unroll
    for (int nt = 0; nt < NTILES; ++nt) {
        #pragma unroll
        for (int r = 0; r < 4; ++r) {
            int er = w*16 + (l >> 4)*4 + r;
            int d = dst_s[er];
            if (!SELF || src_s[er] != d)
                atomicMaxFloat(&agg[(size_t)d*O + colb + nt*16], acc[nt][r]);
        }
    }
}

// ---- conv1 finalize + max_pool over node pairs (cluster1 = arange//2), plus pos2
__global__ __launch_bounds__(256) void k_x2(const float* __restrict__ x,
                                            const float* __restrict__ pos,
                                            const float* __restrict__ root1,
                                            const float* __restrict__ bias1,
                                            float* ws) {
    __shared__ float xs[512];
    int tid = threadIdx.x;
    int n0 = blockIdx.x*16;                      // 16 node rows per block
    for (int idx = tid; idx < 512; idx += 256) xs[idx] = x[n0*32 + idx];
    __syncthreads();
    int o = tid & 31, ci = tid >> 5;             // 8 clusters per block
    int c = blockIdx.x*8 + ci;                   // 25000 = 8*3125 exact
    float b = bias1[o];
    float acc0 = b, acc1 = b;
    const float* x0 = xs + (2*ci)*32;
    const float* x1 = xs + (2*ci+1)*32;
    #pragma unroll
    for (int i = 0; i < 32; ++i) {
        float rw = root1[i*32+o];
        acc0 += x0[i]*rw; acc1 += x1[i]*rw;
    }
    float v0 = ws[OFF_AGG1 + (size_t)(2*c)*32 + o];
    float v1 = ws[OFF_AGG1 + (size_t)(2*c+1)*32 + o];
    if (v0 == -__builtin_inff()) v0 = 0.0f;
    if (v1 == -__builtin_inff()) v1 = 0.0f;
    v0 = eluf(v0 + acc0); v1 = eluf(v1 + acc1);
    ws[OFF_X2 + c*32 + o] = fmaxf(v0, v1);
    if (o < 2) ws[OFF_POS2 + c*2 + o] = 0.5f*(pos[(2*c)*2 + o] + pos[(2*c+1)*2 + o]);
}

// ---- pooled-graph Cartesian: cart + global max (src2/dst2 = idx>>1 on the fly)
__global__ void k_cart(const int* __restrict__ eidx, float* ws) {
    int e = blockIdx.x*256 + threadIdx.x;
    float m = 0.0f;
    if (e < N_EDGES) {
        int s2 = eidx[e] >> 1, d2 = eidx[N_EDGES+e] >> 1;
        float cx = ws[OFF_POS2 + d2*2]     - ws[OFF_POS2 + s2*2];
        float cy = ws[OFF_POS2 + d2*2 + 1] - ws[OFF_POS2 + s2*2 + 1];
        ws[OFF_CART + e*2] = cx; ws[OFF_CART + e*2 + 1] = cy;
        m = fmaxf(fabsf(cx), fabsf(cy));
    }
    #pragma unroll
    for (int off = 32; off; off >>= 1) m = fmaxf(m, __shfl_xor(m, off));
    if ((threadIdx.x & 63) == 0) atomicMax((int*)(ws+OFF_CMAX), __float_as_int(m));
}

// ---- conv2 finalize + max_pool_x over cluster pairs (cluster2 = arange//2)
__global__ __launch_bounds__(256) void k_x4(const float* __restrict__ root2,
                                            const float* __restrict__ bias2,
                                            float* ws) {
    __shared__ float xs[256];
    int tid = threadIdx.x;
    int r0 = blockIdx.x*8;                       // 8 X2 rows per block
    xs[tid] = ws[OFF_X2 + r0*32 + tid];
    __syncthreads();
    int o = tid & 63, ci = tid >> 6;             // 4 out-clusters per block
    int c2 = blockIdx.x*4 + ci;                  // 12500 = 4*3125 exact
    float b = bias2[o];
    float acc0 = b, acc1 = b;
    const float* x0 = xs + (2*ci)*32;
    const float* x1 = xs + (2*ci+1)*32;
    #pragma unroll
    for (int i = 0; i < 32; ++i) {
        float rw = root2[i*64+o];
        acc0 += x0[i]*rw; acc1 += x1[i]*rw;
    }
    float v0 = ws[OFF_AGG2 + (size_t)(2*c2)*64 + o];
    float v1 = ws[OFF_AGG2 + (size_t)(2*c2+1)*64 + o];
    if (v0 == -__builtin_inff()) v0 = 0.0f;
    if (v1 == -__builtin_inff()) v1 = 0.0f;
    v0 = eluf(v0 + acc0); v1 = eluf(v1 + acc1);
    ws[OFF_X4 + c2*64 + o] = fmaxf(v0, v1);
}

// ---- global mean pool: run-length pre-aggregation; batch3[c] = batch[4c+3] (sorted)
__global__ __launch_bounds__(256) void k_gpool(const int* __restrict__ batch, float* ws) {
    int tid = threadIdx.x;
    int o = tid & 63, cl = tid >> 6;
    const int CPB = (C2N + GPB - 1) / GPB;       // 98
    int c0 = blockIdx.x * CPB;
    int c1 = c0 + CPB; if (c1 > C2N) c1 = C2N;
    float acc = 0.0f, cnt = 0.0f;
    int curb = -1;
    for (int c = c0 + cl; c < c1; c += 4) {
        int b = batch[4*c + 3];
        float v = ws[OFF_X4 + c*64 + o];
        if (b != curb) {
            if (curb >= 0) {
                atomicAdd(&ws[OFF_GSUM + curb*64 + o], acc);
                if (o == 0) atomicAdd(&ws[OFF_GCNT + curb], cnt);
            }
            curb = b; acc = 0.0f; cnt = 0.0f;
        }
        acc += v; cnt += 1.0f;
    }
    if (curb >= 0) {
        atomicAdd(&ws[OFF_GSUM + curb*64 + o], acc);
        if (o == 0) atomicAdd(&ws[OFF_GCNT + curb], cnt);
    }
}

__global__ __launch_bounds__(256) void k_head(
    const float* __restrict__ fc1w, const float* __restrict__ fc1b,
    const float* __restrict__ fc2w, const float* __restrict__ fc2b,
    const float* __restrict__ ws, float* __restrict__ out) {
    __shared__ float g_s[32*64], h_s[32*128], l_s[32*32];
    int tid = threadIdx.x;
    for (int idx = tid; idx < 32*64; idx += 256) {
        int b = idx >> 6;
        g_s[idx] = ws[OFF_GSUM + idx] / fmaxf(ws[OFF_GCNT + b], 1.0f);
    }
    __syncthreads();
    for (int idx = tid; idx < 32*128; idx += 256) {
        int b = idx >> 7, f = idx & 127;
        float a = fc1b[f];
        #pragma unroll 8
        for (int i = 0; i < 64; ++i) a += g_s[b*64+i]*fc1w[i*128+f];
        h_s[idx] = eluf(a);
    }
    __syncthreads();
    for (int idx = tid; idx < 32*32; idx += 256) {
        int b = idx >> 5, o = idx & 31;
        float a = fc2b[o];
        #pragma unroll 8
        for (int i = 0; i < 128; ++i) a += h_s[b*128+i]*fc2w[i*32+o];
        l_s[idx] = a;
    }
    __syncthreads();
    if (tid < 32) {
        int b = tid;
        float m = -__builtin_inff();
        for (int o = 0; o < 32; ++o) m = fmaxf(m, l_s[b*32+o]);
        float s = 0.0f;
        for (int o = 0; o < 32; ++o) s += expf(l_s[b*32+o]-m);
        float lg = logf(s);
        for (int o = 0; o < 32; ++o) out[b*32+o] = l_s[b*32+o]-m-lg;
    }
}

extern "C" void kernel_launch(void* const* d_in, const int* in_sizes, int n_in,
                              void* d_out, int out_size, void* d_ws, size_t ws_size,
                              hipStream_t stream) {
    const float* x    = (const float*)d_in[0];
    const float* pos  = (const float*)d_in[1];
    const float* ea   = (const float*)d_in[2];
    const int*   eidx = (const int*)  d_in[3];
    const int*   batch= (const int*)  d_in[4];
    const float* n1w1 = (const float*)d_in[7];
    const float* n1b1 = (const float*)d_in[8];
    const float* n1w2 = (const float*)d_in[9];
    const float* n1b2 = (const float*)d_in[10];
    const float* root1= (const float*)d_in[11];
    const float* bias1= (const float*)d_in[12];
    const float* n2w1 = (const float*)d_in[13];
    const float* n2b1 = (const float*)d_in[14];
    const float* n2w2 = (const float*)d_in[15];
    const float* n2b2 = (const float*)d_in[16];
    const float* root2= (const float*)d_in[17];
    const float* bias2= (const float*)d_in[18];
    const float* fc1w = (const float*)d_in[19];
    const float* fc1b = (const float*)d_in[20];
    const float* fc2w = (const float*)d_in[21];
    const float* fc2b = (const float*)d_in[22];
    float* ws  = (float*)d_ws;
    float* out = (float*)d_out;
    unsigned short* Bb1 = (unsigned short*)(ws + OFF_BB1);
    unsigned short* Bb2 = (unsigned short*)(ws + OFF_BB2);

    hipLaunchKernelGGL(k_init, dim3((ZERO_END+255)/256), dim3(256), 0, stream, ws);
    hipLaunchKernelGGL((k_swzf<32>), dim3(104), dim3(256), 0, stream, n1w2, n1b2, Bb1);
    hipLaunchKernelGGL((k_swzf<64>), dim3(208), dim3(256), 0, stream, n2w2, n2b2, Bb2);
    // conv1: [E x 832] @ [832 x 32]
    hipLaunchKernelGGL((k_edgemm<32, 2, 0, 0, 0, 0>), dim3(N_EDGES/EPB), dim3(512), 0, stream,
                       x, Bb1, n1w1, n1b1, eidx, eidx + N_EDGES, ea,
                       (const float*)nullptr, ws + OFF_AGG1);
    hipLaunchKernelGGL(k_x2, dim3(C1N/8), dim3(256), 0, stream, x, pos, root1, bias1, ws);
    hipLaunchKernelGGL(k_cart, dim3(N_EDGES/256), dim3(256), 0, stream, eidx, ws);
    // conv2: [E x 832] @ [832 x 64], two dispatches of 32 cols (LDS budget)
    hipLaunchKernelGGL((k_edgemm<64, 2, 0, 1, 1, 1>), dim3(N_EDGES/EPB), dim3(512), 0, stream,
                       ws + OFF_X2, Bb2, n2w1, n2b1, eidx, eidx + N_EDGES,
                       ws + OFF_CART, ws + OFF_CMAX, ws + OFF_AGG2);
    hipLaunchKernelGGL((k_edgemm<64, 2, 2, 1, 1, 1>), dim3(N_EDGES/EPB), dim3(512), 0, stream,
                       ws + OFF_X2, Bb2, n2w1, n2b1, eidx, eidx + N_EDGES,
                       ws + OFF_CART, ws + OFF_CMAX, ws + OFF_AGG2);
    hipLaunchKernelGGL(k_x4, dim3(C2N/4), dim3(256), 0, stream, root2, bias2, ws);
    hipLaunchKernelGGL(k_gpool, dim3(GPB), dim3(256), 0, stream, batch, ws);
    hipLaunchKernelGGL(k_head, dim3(1), dim3(256), 0, stream,
                       fc1w, fc1b, fc2w, fc2b, ws, out);
}